// Round 3
// baseline (389.714 us; speedup 1.0000x reference)
//
#include <hip/hip_runtime.h>
#include <hip/hip_bf16.h>
#include <stdint.h>

// ---------- types ----------
typedef __attribute__((ext_vector_type(8)))  short bf16x8;
typedef __attribute__((ext_vector_type(4)))  float f32x4;
typedef __attribute__((ext_vector_type(4)))  float float4v;
typedef __attribute__((ext_vector_type(8)))  unsigned short u16x8;

#define MFMA16(a,b,c) __builtin_amdgcn_mfma_f32_16x16x32_bf16((a),(b),(c),0,0,0)

__device__ __forceinline__ unsigned short f2bf(float f) {
    unsigned int u = __builtin_bit_cast(unsigned int, f);
    u = (u + 0x7fffu + ((u >> 16) & 1u)) >> 16;
    return (unsigned short)u;
}

__device__ __forceinline__ void gload_lds16(const void* g, void* l) {
    __builtin_amdgcn_global_load_lds(
        (const __attribute__((address_space(1))) void*)g,
        (__attribute__((address_space(3))) void*)l, 16, 0, 0);
}

template<int N> __device__ __forceinline__ void waitvm() {}  // N<0: no wait
template<> __device__ __forceinline__ void waitvm<6>() { asm volatile("s_waitcnt vmcnt(6)" ::: "memory"); }
template<> __device__ __forceinline__ void waitvm<4>() { asm volatile("s_waitcnt vmcnt(4)" ::: "memory"); }
template<> __device__ __forceinline__ void waitvm<2>() { asm volatile("s_waitcnt vmcnt(2)" ::: "memory"); }
template<> __device__ __forceinline__ void waitvm<0>() { asm volatile("s_waitcnt vmcnt(0)" ::: "memory"); }

// ---------- fp32 -> bf16 convert ----------
__global__ void cvt_f32_bf16(const float* __restrict__ in, unsigned short* __restrict__ out, long n) {
    long i = ((long)blockIdx.x * blockDim.x + threadIdx.x) * 8;
    long stride = (long)gridDim.x * blockDim.x * 8;
    for (; i < n; i += stride) {
        float4v v0 = *(const float4v*)(in + i);
        float4v v1 = *(const float4v*)(in + i + 4);
        u16x8 o;
        o[0] = f2bf(v0[0]); o[1] = f2bf(v0[1]); o[2] = f2bf(v0[2]); o[3] = f2bf(v0[3]);
        o[4] = f2bf(v1[0]); o[5] = f2bf(v1[1]); o[6] = f2bf(v1[2]); o[7] = f2bf(v1[3]);
        *(u16x8*)(out + i) = o;
    }
}

// ---------- Fused GEMM: z = H @ VT^T (256x256 tile, 8-phase), then per-wave
// grouped up-projection out = z @ U[g]^T fused in the epilogue. ----------
// M=16384, N(=sum_ranks)=2048, K=4096. 8 waves (2M x 4N), per-wave z = 128x64.
// Wave (wr,wc) owns z rows wr*128..+127, r-cols wc*64..+63 == group (bid&7)*4+wc.
// LDS: 2 x (A 256x64 + B 256x64) bf16 = 128 KiB; reused by epilogue as 8 x 16 KiB
// per-wave z buffers (no cross-wave traffic -> no barrier needed after final BAR2).

#define STAGE_A(nA_, k0n, h, l) \
    gload_lds16(pA + ((l)*128 + (h)*64) * 4096L + (k0n), (nA_) + dA0 + ((l)*128 + (h)*64) * 64)
#define STAGE_B(nB_, k0n, h, l) \
    gload_lds16(pB + ((l)*128 + (h)*32) * 4096L + (k0n), (nB_) + dB0 + ((l)*128 + (h)*32) * 64)

#define LDA(sA_, QM) do { _Pragma("unroll") for (int mi = 0; mi < 4; ++mi) { \
    a[mi][0] = *(const bf16x8*)((sA_) + ((wr*128 + (QM)*64 + mi*16 + lan15) << 6) + g0); \
    a[mi][1] = *(const bf16x8*)((sA_) + ((wr*128 + (QM)*64 + mi*16 + lan15) << 6) + (g0 ^ 32)); } } while (0)
#define LDB(sB_, QN) do { _Pragma("unroll") for (int ni = 0; ni < 2; ++ni) { \
    b[ni][0] = *(const bf16x8*)((sB_) + ((wc*64 + (QN)*32 + ni*16 + lan15) << 6) + g0); \
    b[ni][1] = *(const bf16x8*)((sB_) + ((wc*64 + (QN)*32 + ni*16 + lan15) << 6) + (g0 ^ 32)); } } while (0)

#define DOMFMA(QM, QN) do { __builtin_amdgcn_s_setprio(1); \
    _Pragma("unroll") for (int mi = 0; mi < 4; ++mi) \
      _Pragma("unroll") for (int ni = 0; ni < 2; ++ni) { \
        acc[(QM)*4+mi][(QN)*2+ni] = MFMA16(a[mi][0], b[ni][0], acc[(QM)*4+mi][(QN)*2+ni]); \
        acc[(QM)*4+mi][(QN)*2+ni] = MFMA16(a[mi][1], b[ni][1], acc[(QM)*4+mi][(QN)*2+ni]); } \
    __builtin_amdgcn_s_setprio(0); } while (0)

#define BAR1() do { __builtin_amdgcn_s_barrier(); \
    asm volatile("s_waitcnt lgkmcnt(0)" ::: "memory"); \
    __builtin_amdgcn_sched_barrier(0); } while (0)
#define BAR2() do { __builtin_amdgcn_s_barrier(); \
    __builtin_amdgcn_sched_barrier(0); } while (0)

#define KTILE(sA_, sB_, nA_, nB_, k0n, DOSTAGE, V0, V1, V3) do { \
    LDA(sA_, 0); LDB(sB_, 0); \
    if (DOSTAGE) { STAGE_A(nA_, k0n, 0, 0); STAGE_A(nA_, k0n, 0, 1); \
                   STAGE_B(nB_, k0n, 0, 0); STAGE_B(nB_, k0n, 0, 1); } \
    BAR1(); DOMFMA(0, 0); waitvm<V0>(); BAR2(); \
    LDB(sB_, 1); \
    if (DOSTAGE) { STAGE_B(nB_, k0n, 1, 0); STAGE_B(nB_, k0n, 1, 1); } \
    BAR1(); DOMFMA(0, 1); waitvm<V1>(); BAR2(); \
    LDA(sA_, 1); \
    if (DOSTAGE) { STAGE_A(nA_, k0n, 1, 0); STAGE_A(nA_, k0n, 1, 1); } \
    BAR1(); DOMFMA(1, 1); BAR2(); \
    LDB(sB_, 0); \
    BAR1(); DOMFMA(1, 0); waitvm<V3>(); BAR2(); \
} while (0)

__global__ __launch_bounds__(512, 2) void gemm_fused(const unsigned short* __restrict__ A,  // [16384][4096]
                                                     const unsigned short* __restrict__ B,  // [2048][4096]
                                                     const float* __restrict__ Uw,          // [32][128][64]
                                                     float* __restrict__ out) {             // [16384][4096]
    __shared__ __align__(16) unsigned short lds[65536];   // 128 KiB

    const int tid   = threadIdx.x;
    const int lane  = tid & 63;
    const int wid   = tid >> 6;
    const int wr    = wid >> 2;          // 0..1
    const int wc    = wid & 3;           // 0..3
    const int lan15 = lane & 15;
    const int g0    = (((lane >> 4) ^ (lane & 7)) << 3);

    const int  bid = blockIdx.x;
    const long m0  = (long)(bid >> 3) * 256;
    const long n0  = (long)(bid & 7) * 256;

    const int q8    = tid >> 3;
    const int granA = (((tid & 7) ^ (q8 & 7)) << 3);
    const unsigned short* pA = A + (m0 + q8) * 4096L + granA;
    const int rB0   = (q8 & 31) + ((q8 >> 5) << 6);
    const unsigned short* pB = B + (n0 + rB0) * 4096L + granA;
    const int dA0   = (wid * 8) * 64;
    const int dB0   = ((wid & 3) * 8 + ((wid >> 2) << 6)) * 64;

    f32x4 acc[8][4] = {};
    bf16x8 a[4][2], b[2][2];

    unsigned short* buf0 = lds;
    unsigned short* buf1 = lds + 32768;

    STAGE_A(buf0, 0, 0, 0); STAGE_A(buf0, 0, 0, 1);
    STAGE_B(buf0 + 16384, 0, 0, 0); STAGE_B(buf0 + 16384, 0, 0, 1);
    STAGE_B(buf0 + 16384, 0, 1, 0); STAGE_B(buf0 + 16384, 0, 1, 1);
    STAGE_A(buf0, 0, 1, 0); STAGE_A(buf0, 0, 1, 1);
    waitvm<4>();
    BAR2();

    for (int t = 0; t < 63; ++t) {
        unsigned short* cb = (t & 1) ? buf1 : buf0;
        unsigned short* nb = (t & 1) ? buf0 : buf1;
        KTILE(cb, cb + 16384, nb, nb + 16384, (t + 1) * 64, true, 6, 6, 4);
    }
    KTILE(buf1, buf1 + 16384, buf0, buf0 + 16384, 0, false, 2, 0, -1);

    // ==== fused grouped up-projection epilogue ====
    // out[m, g*128+d] = sum_r z[m, g*64+r] * U[g][d][r], g = (bid&7)*4 + wc.
    // Per-wave private LDS z buffer [128 m][64 r] bf16, granule-XOR swizzled.
    {
        unsigned short* zw = lds + wid * 8192;
        const int q = lane >> 4;

        // 1) dump acc -> LDS bf16 (swizzled granules: phys = (r>>3) ^ (m&7))
        #pragma unroll
        for (int mi = 0; mi < 8; ++mi) {
            #pragma unroll
            for (int ni = 0; ni < 4; ++ni) {
                #pragma unroll
                for (int j = 0; j < 4; ++j) {
                    const int ml = mi * 16 + q * 4 + j;
                    const int gr = (ni * 2 + (lan15 >> 3)) ^ (ml & 7);
                    zw[ml * 64 + gr * 8 + (lan15 & 7)] = f2bf(acc[mi][ni][j]);
                }
            }
        }

        // 2) preload U[g] A-operand fragments from global (fp32 -> bf16 in reg):
        //    row d = df*16 + lan15, k-elems r = rk*32 + q*8 .. +7
        const int g_blk = (bid & 7) * 4 + wc;
        const float* ug = Uw + (long)g_blk * 8192;
        bf16x8 ua[2][8];
        #pragma unroll
        for (int df = 0; df < 8; ++df) {
            #pragma unroll
            for (int rk = 0; rk < 2; ++rk) {
                const float* up = ug + (df * 16 + lan15) * 64 + rk * 32 + q * 8;
                float4v u0 = *(const float4v*)up;
                float4v u1 = *(const float4v*)(up + 4);
                u16x8 t;
                t[0] = f2bf(u0[0]); t[1] = f2bf(u0[1]); t[2] = f2bf(u0[2]); t[3] = f2bf(u0[3]);
                t[4] = f2bf(u1[0]); t[5] = f2bf(u1[1]); t[6] = f2bf(u1[2]); t[7] = f2bf(u1[3]);
                ua[rk][df] = __builtin_bit_cast(bf16x8, t);
            }
        }

        // 3) out^T[d][m] = U . z^T : D = MFMA(A=U-frag, B=z-frag).
        //    C/D: col = m = lan15, row = d = q*4 + jreg  -> jreg contiguous in d
        //    => float4 stores, 64B-per-row coalescing.
        const long mwb  = m0 + wr * 128;
        const long ocol = (long)g_blk * 128;
        #pragma unroll
        for (int mf = 0; mf < 8; ++mf) {
            f32x4 a2[8] = {};
            #pragma unroll
            for (int rk = 0; rk < 2; ++rk) {
                const int ml = mf * 16 + lan15;
                const int gr = (rk * 4 + q) ^ (ml & 7);
                const bf16x8 zb = *(const bf16x8*)&zw[ml * 64 + gr * 8];
                #pragma unroll
                for (int df = 0; df < 8; ++df)
                    a2[df] = MFMA16(ua[rk][df], zb, a2[df]);
            }
            #pragma unroll
            for (int df = 0; df < 8; ++df)
                *(float4v*)&out[(mwb + mf * 16 + lan15) * 4096L + ocol + df * 16 + q * 4] = a2[df];
        }
    }
}

// ---------- launch ----------
extern "C" void kernel_launch(void* const* d_in, const int* in_sizes, int n_in,
                              void* d_out, int out_size, void* d_ws, size_t ws_size,
                              hipStream_t stream) {
    const float* hs = (const float*)d_in[0];   // [4,4096,4096]
    const float* vt = (const float*)d_in[1];   // [2048,4096]
    const float* uw = (const float*)d_in[2];   // [32,128,64]
    float* out = (float*)d_out;

    unsigned short* hs_bf = (unsigned short*)d_ws;
    unsigned short* vt_bf = hs_bf + 67108864L;

    cvt_f32_bf16<<<2048, 256, 0, stream>>>(hs, hs_bf, 67108864L);
    cvt_f32_bf16<<<512, 256, 0, stream>>>(vt, vt_bf, 8388608L);

    // (16384/256) x (2048/256) = 64 x 8 = 512 blocks, 512 threads
    gemm_fused<<<512, 512, 0, stream>>>(hs_bf, vt_bf, uw, out);
}